// Round 4
// baseline (3974.541 us; speedup 1.0000x reference)
//
#include <hip/hip_runtime.h>

#define B_   4
#define P_   16384
#define HID_ 64
#define M_   256
#define J_   65   // 64 features + constant

__device__ __forceinline__ float gelu_f(float x){
    return 0.5f * x * (1.0f + erff(x * 0.70710678118654752440f));
}

// ---------------- lift: h0[b][o][p] = lift_w[o]·[x0,x1,x2,gh,gw] + lift_b[o] ----------------
__global__ __launch_bounds__(256) void k_lift(const float* __restrict__ x,
        const float* __restrict__ lw, const float* __restrict__ lb,
        float* __restrict__ h0){
    __shared__ float lwl[320];
    __shared__ float lbl[64];
    int tid = threadIdx.x;
    for (int i = tid; i < 320; i += 256) lwl[i] = lw[i];
    if (tid < 64)  lbl[tid] = lb[tid];
    __syncthreads();
    int t = blockIdx.x*256 + tid;
    int b = t >> 14, p = t & (P_-1);
    float gh = (float)(p >> 7) * (1.0f/127.0f);
    float gw = (float)(p & 127) * (1.0f/127.0f);
    const float* xb = x + (size_t)b*3*P_ + p;
    float x0 = xb[0], x1 = xb[P_], x2 = xb[2*P_];
    float* hb = h0 + (size_t)b*64*P_ + p;
    #pragma unroll
    for (int o = 0; o < 64; ++o){
        const float* w = lwl + o*5;
        float v = lbl[o] + w[0]*x0 + w[1]*x1 + w[2]*x2 + w[3]*gh + w[4]*gw;
        hb[(size_t)o*P_] = v;
    }
}

// ---------------- per-pixel MLP: A[b][p][j] = gelu(gelu([gh,gw,h]·w0+b0)·w1+b1) ----------------
__global__ __launch_bounds__(256) void k_mlp(const float* __restrict__ h0,
        const float* __restrict__ w0, const float* __restrict__ b0,
        const float* __restrict__ w1, const float* __restrict__ b1,
        float* __restrict__ A){
    __shared__ float wl[4288];
    int tid = threadIdx.x;
    int t = blockIdx.x*256 + tid;
    int b = t >> 14, p = t & (P_-1);
    for (int i = tid; i < 4224; i += 256) wl[i] = w0[i];
    if (tid < 64) wl[4224+tid] = b0[tid];
    __syncthreads();
    float gh = (float)(p >> 7)*(1.0f/127.0f), gw = (float)(p & 127)*(1.0f/127.0f);
    float z0[64];
    #pragma unroll
    for (int j = 0; j < 64; ++j) z0[j] = wl[4224+j];
    {
        const float4* wa = (const float4*)(wl);
        const float4* wb = (const float4*)(wl + 64);
        #pragma unroll
        for (int j4 = 0; j4 < 16; ++j4){
            float4 a = wa[j4], c = wb[j4];
            z0[j4*4+0] += gh*a.x + gw*c.x;
            z0[j4*4+1] += gh*a.y + gw*c.y;
            z0[j4*4+2] += gh*a.z + gw*c.z;
            z0[j4*4+3] += gh*a.w + gw*c.w;
        }
    }
    const float* hb = h0 + (size_t)b*64*P_ + p;
    #pragma unroll 1
    for (int c = 2; c < 66; ++c){
        float v = hb[(size_t)(c-2)*P_];
        const float4* wr = (const float4*)(wl + c*64);
        #pragma unroll
        for (int j4 = 0; j4 < 16; ++j4){
            float4 w = wr[j4];
            z0[j4*4+0] += v*w.x; z0[j4*4+1] += v*w.y;
            z0[j4*4+2] += v*w.z; z0[j4*4+3] += v*w.w;
        }
    }
    #pragma unroll
    for (int j = 0; j < 64; ++j) z0[j] = gelu_f(z0[j]);
    __syncthreads();
    for (int i = tid; i < 4096; i += 256) wl[i] = w1[i];
    if (tid < 64) wl[4096+tid] = b1[tid];
    __syncthreads();
    float z1[64];
    #pragma unroll
    for (int j = 0; j < 64; ++j) z1[j] = wl[4096+j];
    #pragma unroll
    for (int c = 0; c < 64; ++c){
        float v = z0[c];
        const float4* wr = (const float4*)(wl + c*64);
        #pragma unroll
        for (int j4 = 0; j4 < 16; ++j4){
            float4 w = wr[j4];
            z1[j4*4+0] += v*w.x; z1[j4*4+1] += v*w.y;
            z1[j4*4+2] += v*w.z; z1[j4*4+3] += v*w.w;
        }
    }
    float4* Ao = (float4*)(A + ((size_t)b*P_ + p)*64);
    #pragma unroll
    for (int j4 = 0; j4 < 16; ++j4){
        float4 o4;
        o4.x = gelu_f(z1[j4*4+0]); o4.y = gelu_f(z1[j4*4+1]);
        o4.z = gelu_f(z1[j4*4+2]); o4.w = gelu_f(z1[j4*4+3]);
        Ao[j4] = o4;
    }
}

// ---------------- S partials: per 128-pixel chunk, Sp[blk][i*65+j] = sum_q A65[q][i]A65[q][j] ----------------
__global__ __launch_bounds__(256) void k_sgram_part(const float* __restrict__ A, float* __restrict__ Sp){
    __shared__ float At[128*66];
    int tid = threadIdx.x;
    int b  = blockIdx.x >> 7;
    int p0 = (blockIdx.x & 127) << 7;
    for (int idx = tid; idx < 8192; idx += 256){
        int q = idx >> 6, j = idx & 63;
        At[q*66+j] = A[((size_t)b*P_ + p0 + q)*64 + j];
    }
    if (tid < 128) At[tid*66+64] = 1.0f;
    __syncthreads();
    float* outp = Sp + (size_t)blockIdx.x*4225;
    for (int pi = tid; pi < 4225; pi += 256){
        int i = pi / 65, j = pi % 65;
        float s = 0.f;
        for (int q = 0; q < 128; ++q) s += At[q*66+i]*At[q*66+j];
        outp[pi] = s;
    }
}

// ---------------- S reduce: f64 sum of 128 partials ----------------
__global__ __launch_bounds__(256) void k_sred(const float* __restrict__ Sp, double* __restrict__ Sgd){
    int t = blockIdx.x*256 + threadIdx.x;
    if (t >= B_*4225) return;
    int b = t / 4225, e = t - b*4225;
    const float* sp = Sp + (size_t)b*128*4225 + e;
    double acc = 0.0;
    for (int c = 0; c < 128; ++c) acc += (double)sp[(size_t)c*4225];
    Sgd[t] = acc;
}

// ---------------- k_mgs: f64 Cholesky of S + f32 MGS on d=L^T c + back-substitution u=L^-T d ----------------
// LDS: Ld 4225 f64 (33.8KB) + invd 65 f64 + dk 130 f32 + scal  ~= 34.9KB static
__global__ __launch_bounds__(256) void k_mgs(const double* __restrict__ Sgd,
        const float* __restrict__ wf, const float* __restrict__ bf,
        float2* __restrict__ Ug){
    __shared__ double Ld[4225];
    __shared__ double invd[65];
    __shared__ float dkr[65], dki[65];
    __shared__ float scal;
    int b = blockIdx.x, tid = threadIdx.x, m = tid;
    for (int i = tid; i < 4225; i += 256) Ld[i] = Sgd[b*4225+i];
    __syncthreads();
    double S00 = Ld[0];
    // owned lower-triangle elements (i>=j), 2145 total, <=9 per thread, static slots
    int iiA[9], jjA[9];
    #pragma unroll
    for (int s = 0; s < 9; ++s){
        int e = tid + s*256;
        int i = -1, j = -1;
        if (e < 2145){
            i = (int)((sqrtf(8.0f*(float)e + 1.0f) - 1.0f)*0.5f);
            while ((i+1)*(i+2)/2 <= e) ++i;
            while (i*(i+1)/2 > e) --i;
            j = e - i*(i+1)/2;
        }
        iiA[s] = i; jjA[s] = j;
    }
    // in-place Cholesky (lower triangle), clamped pivots
    for (int k = 0; k < 65; ++k){
        if (tid == 0){
            double piv = Ld[k*65+k];
            double flr = 1e-14 * S00;
            if (!(piv > flr)) piv = flr;
            double l = sqrt(piv);
            Ld[k*65+k] = l;
            invd[k] = 1.0/l;
        }
        __syncthreads();
        { int i = k+1+tid; if (i < 65) Ld[i*65+k] *= invd[k]; }
        __syncthreads();
        #pragma unroll
        for (int s = 0; s < 9; ++s){
            int i = iiA[s], j = jjA[s];
            if (j > k) Ld[i*65+j] -= Ld[i*65+k]*Ld[j*65+k];
        }
        __syncthreads();
    }
    // d_m = L^T c_m  (c streamed from global, never stored)
    float dr[65], di[65];
    #pragma unroll
    for (int i = 0; i < 65; ++i){ dr[i] = 0.f; di[i] = 0.f; }
    #pragma unroll
    for (int j = 0; j < 65; ++j){
        float cjr, cji;
        if (j < 64){ cjr = wf[j*512 + m]; cji = wf[j*512 + 256 + m]; }
        else       { cjr = bf[m];         cji = bf[256 + m]; }
        #pragma unroll
        for (int i = 0; i <= j; ++i){
            float l = (float)Ld[j*65+i];
            dr[i] += l*cjr; di[i] += l*cji;
        }
    }
    __syncthreads();
    // MGS over 256 columns in 65-dim space (exact reference semantics, incl. +1e-8)
    for (int k = 0; k < 256; ++k){
        if (tid == k){
            float ns = 0.f;
            #pragma unroll
            for (int j = 0; j < 65; ++j){
                dkr[j] = dr[j]; dki[j] = di[j];
                ns += dr[j]*dr[j] + di[j]*di[j];
            }
            scal = 1.0f/(sqrtf(ns) + 1e-8f);
        }
        __syncthreads();
        float inv = scal;
        if (m > k){
            float pr = 0.f, pi2 = 0.f;
            #pragma unroll
            for (int j = 0; j < 65; ++j){
                pr  += dkr[j]*dr[j] + dki[j]*di[j];
                pi2 += dkr[j]*di[j] - dki[j]*dr[j];
            }
            float ar = inv*inv*pr, ai = inv*inv*pi2;
            #pragma unroll
            for (int j = 0; j < 65; ++j){
                dr[j] -= dkr[j]*ar - dki[j]*ai;
                di[j] -= dkr[j]*ai + dki[j]*ar;
            }
        } else if (m == k){
            #pragma unroll
            for (int j = 0; j < 65; ++j){ dr[j] *= inv; di[j] *= inv; }
        }
        __syncthreads();
    }
    // back-substitution: solve L^T u = d in place
    #pragma unroll
    for (int j = 64; j >= 0; --j){
        float idj = (float)invd[j];
        float ujr = dr[j]*idj, uji = di[j]*idj;
        dr[j] = ujr; di[j] = uji;
        #pragma unroll
        for (int i = 0; i < j; ++i){
            float l = (float)Ld[j*65+i];
            dr[i] -= l*ujr; di[i] -= l*uji;
        }
    }
    #pragma unroll
    for (int j = 0; j < 65; ++j)
        Ug[b*16640 + (j<<8) + m] = make_float2(dr[j], di[j]);
}

// ---------------- HA partials: 64-pixel chunks, HAp[blk][c*65+j] ----------------
__global__ __launch_bounds__(256) void k_ha_part(const float* __restrict__ h,
        const float* __restrict__ A, float* __restrict__ HAp){
    __shared__ float htl[64*65];
    __shared__ float Atl[64*66];
    int tid = threadIdx.x;
    int b  = blockIdx.x >> 8;
    int p0 = (blockIdx.x & 255) << 6;
    for (int idx = tid; idx < 4096; idx += 256){
        int c = idx >> 6, q = idx & 63;
        htl[c*65+q] = h[((size_t)b*64 + c)*P_ + p0 + q];
    }
    for (int idx = tid; idx < 4096; idx += 256){
        int q = idx >> 6, j = idx & 63;
        Atl[q*66+j] = A[((size_t)b*P_ + p0 + q)*64 + j];
    }
    if (tid < 64) Atl[tid*66+64] = 1.0f;
    __syncthreads();
    float* outp = HAp + (size_t)blockIdx.x*4160;
    for (int pi = tid; pi < 4160; pi += 256){
        int c = pi / 65, j = pi % 65;
        float s = 0.f;
        for (int q = 0; q < 64; ++q) s += htl[c*65+q]*Atl[q*66+j];
        outp[pi] = s;
    }
}

// ---------------- HA reduce: 256 partials ----------------
__global__ __launch_bounds__(256) void k_hred(const float* __restrict__ HAp, float* __restrict__ HA){
    int t = blockIdx.x*256 + threadIdx.x;
    if (t >= B_*4160) return;
    int b = t / 4160, e = t - b*4160;
    const float* hp = HAp + (size_t)b*256*4160 + e;
    double acc = 0.0;
    for (int c = 0; c < 256; ++c) acc += (double)hp[(size_t)c*4160];
    HA[t] = (float)acc;
}

// ---------------- coeff = HA · conj(U) / P ----------------
__global__ __launch_bounds__(256) void k_coeff(const float* __restrict__ HA,
        const float2* __restrict__ Ug,
        float* __restrict__ cRe, float* __restrict__ cIm){
    int t = blockIdx.x*256 + threadIdx.x;
    int b = t >> 14, c = (t >> 8) & 63, m = t & 255;
    const float*  ha = HA + b*4160 + c*65;
    const float2* u  = Ug + b*16640 + m;
    float sr = 0.f, si = 0.f;
    for (int j = 0; j < 65; ++j){
        float hv = ha[j];
        float2 uv = u[j<<8];
        sr += hv*uv.x; si += hv*uv.y;
    }
    cRe[t] =  sr * (1.0f/16384.0f);
    cIm[t] = -si * (1.0f/16384.0f);
}

// ---------------- mixed[b,o,m] = sum_c coeff[b,c,m] * (wr + i wi) ----------------
__global__ __launch_bounds__(256) void k_mixed(const float* __restrict__ cRe, const float* __restrict__ cIm,
        const float* __restrict__ wr, const float* __restrict__ wi,
        float* __restrict__ mRe, float* __restrict__ mIm){
    int t = blockIdx.x*256 + threadIdx.x;
    int b = t >> 14, o = (t >> 8) & 63, m = t & 255;
    const float* cr  = cRe + b*16384 + m;
    const float* ci  = cIm + b*16384 + m;
    const float* wrp = wr + o*256 + m;
    const float* wip = wi + o*256 + m;
    float ar = 0.f, ai = 0.f;
    for (int c = 0; c < 64; ++c){
        float crv = cr[c<<8], civ = ci[c<<8];
        float wrv = wrp[(size_t)c<<14], wiv = wip[(size_t)c<<14];
        ar += crv*wrv - civ*wiv;
        ai += crv*wiv + civ*wrv;
    }
    mRe[t] = ar; mIm[t] = ai;
}

// ---------------- WA[o][j] = Re( sum_m mixed[o,m] * U[j,m] ) ----------------
__global__ __launch_bounds__(256) void k_wa(const float* __restrict__ mRe, const float* __restrict__ mIm,
        const float2* __restrict__ Ug, float* __restrict__ WA){
    int t = blockIdx.x*256 + threadIdx.x;
    if (t >= B_*4160) return;
    int b = t / 4160;
    int r = t - b*4160;
    int o = r / 65, j = r % 65;
    const float*  mr = mRe + b*16384 + o*256;
    const float*  mi = mIm + b*16384 + o*256;
    const float2* u  = Ug + b*16640 + (j<<8);
    float s = 0.f;
    for (int m = 0; m < 256; ++m){
        float2 uv = u[m];
        s += mr[m]*uv.x - mi[m]*uv.y;
    }
    WA[t] = s;
}

// ---------------- y = WA·A65^T ; z = y + skip(h) ; LN ; GELU ----------------
__global__ __launch_bounds__(256) void k_yfuse(const float* __restrict__ A,
        const float* __restrict__ WAg, const float* __restrict__ hin,
        const float* __restrict__ sw, const float* __restrict__ sb,
        const float* __restrict__ gam, const float* __restrict__ bet,
        float* __restrict__ hout){
    __shared__ float WAt[4096];   // [j][o]
    __shared__ float swT[4096];   // [c][o]
    __shared__ float WAc[64], sbl[64], gl[64], bl[64];
    int tid = threadIdx.x;
    int b = blockIdx.x >> 6;
    int p = ((blockIdx.x & 63) << 8) + tid;
    const float* wab = WAg + b*4160;
    for (int idx = tid; idx < 4096; idx += 256){
        int j = idx >> 6, o = idx & 63;
        WAt[idx] = wab[o*65 + j];
        swT[idx] = sw[o*64 + j];
    }
    if (tid < 64){ WAc[tid] = wab[tid*65+64]; sbl[tid] = sb[tid]; gl[tid] = gam[tid]; bl[tid] = bet[tid]; }
    __syncthreads();
    float acc[64];
    #pragma unroll
    for (int o = 0; o < 64; ++o) acc[o] = 0.f;
    const float4* Ar = (const float4*)(A + ((size_t)b*P_ + p)*64);
    #pragma unroll 1
    for (int j4 = 0; j4 < 16; ++j4){
        float4 av = Ar[j4];
        const float* w0p = WAt + (j4*4+0)*64;
        const float* w1p = WAt + (j4*4+1)*64;
        const float* w2p = WAt + (j4*4+2)*64;
        const float* w3p = WAt + (j4*4+3)*64;
        #pragma unroll
        for (int o = 0; o < 64; ++o)
            acc[o] += av.x*w0p[o] + av.y*w1p[o] + av.z*w2p[o] + av.w*w3p[o];
    }
    #pragma unroll 1
    for (int c = 0; c < 64; ++c){
        float hv = hin[((size_t)b*64+c)*P_ + p];
        const float* wrow = swT + c*64;
        #pragma unroll
        for (int o = 0; o < 64; ++o) acc[o] += hv*wrow[o];
    }
    float mu = 0.f;
    #pragma unroll
    for (int o = 0; o < 64; ++o){ acc[o] += WAc[o] + sbl[o]; mu += acc[o]; }
    mu *= (1.0f/64.0f);
    float var = 0.f;
    #pragma unroll
    for (int o = 0; o < 64; ++o){ float d = acc[o]-mu; var += d*d; }
    var *= (1.0f/64.0f);
    float rs = 1.0f/sqrtf(var + 1e-6f);
    float* hb = hout + (size_t)b*64*P_ + p;
    #pragma unroll
    for (int o = 0; o < 64; ++o){
        float zn = (acc[o]-mu)*rs*gl[o] + bl[o];
        hb[(size_t)o*P_] = gelu_f(zn);
    }
}

// ---------------- final projection ----------------
__global__ __launch_bounds__(256) void k_proj(const float* __restrict__ h,
        const float* __restrict__ pw, const float* __restrict__ pb,
        float* __restrict__ out){
    int t = blockIdx.x*256 + threadIdx.x;
    int b = t >> 14, p = t & (P_-1);
    const float* hb = h + (size_t)b*64*P_ + p;
    float s = pb[0];
    for (int c = 0; c < 64; ++c) s += pw[c]*hb[(size_t)c*P_];
    out[t] = s;
}

extern "C" void kernel_launch(void* const* d_in, const int* in_sizes, int n_in,
                              void* d_out, int out_size, void* d_ws, size_t ws_size,
                              hipStream_t stream){
    const float* x      = (const float*)d_in[0];
    const float* lift_w = (const float*)d_in[1];
    const float* lift_b = (const float*)d_in[2];
    const float* w0     = (const float*)d_in[3];
    const float* b0     = (const float*)d_in[4];
    const float* w1     = (const float*)d_in[5];
    const float* b1     = (const float*)d_in[6];
    const float* wf     = (const float*)d_in[7];
    const float* bf     = (const float*)d_in[8];
    const float* wr0 = (const float*)d_in[9];
    const float* wi0 = (const float*)d_in[10];
    const float* sw0 = (const float*)d_in[11];
    const float* sb0 = (const float*)d_in[12];
    const float* g0  = (const float*)d_in[13];
    const float* be0 = (const float*)d_in[14];
    const float* wr1 = (const float*)d_in[15];
    const float* wi1 = (const float*)d_in[16];
    const float* sw1 = (const float*)d_in[17];
    const float* sb1 = (const float*)d_in[18];
    const float* g1  = (const float*)d_in[19];
    const float* be1 = (const float*)d_in[20];
    const float* pw  = (const float*)d_in[21];
    const float* pb  = (const float*)d_in[22];
    float* out = (float*)d_out;
    float* ws = (float*)d_ws;

    float*  h0  = ws;                        // 4,194,304 f
    float*  h1  = ws + 4194304;              // 4,194,304 f
    float*  A   = ws + 8388608;              // 4,194,304 f
    float*  R   = ws + 12582912;             // union: Sp (512*4225) / HAp (1024*4160)
    double* Sgd = (double*)(ws + 16842752);  // 16,900 f64 (8B-aligned: idx even)
    float*  HA  = ws + 16876552;             // 16,640 f
    float2* Ug  = (float2*)(ws + 16893192);  // 16,640 float2 (idx even)
    float*  cRe = ws + 16926472;             // 65,536 f
    float*  cIm = ws + 16992008;
    float*  mRe = ws + 17057544;
    float*  mIm = ws + 17123080;
    float*  WA  = ws + 17188616;             // 16,640 f  -> total 17,205,256 f (~69 MB)
    (void)ws_size; (void)in_sizes; (void)n_in; (void)out_size;

    k_lift<<<256,256,0,stream>>>(x, lift_w, lift_b, h0);
    k_mlp<<<256,256,0,stream>>>(h0, w0, b0, w1, b1, A);
    k_sgram_part<<<512,256,0,stream>>>(A, R);
    k_sred<<<67,256,0,stream>>>(R, Sgd);
    k_mgs<<<4,256,0,stream>>>(Sgd, wf, bf, Ug);

    // block 0
    k_ha_part<<<1024,256,0,stream>>>(h0, A, R);
    k_hred<<<65,256,0,stream>>>(R, HA);
    k_coeff<<<256,256,0,stream>>>(HA, Ug, cRe, cIm);
    k_mixed<<<256,256,0,stream>>>(cRe, cIm, wr0, wi0, mRe, mIm);
    k_wa<<<65,256,0,stream>>>(mRe, mIm, Ug, WA);
    k_yfuse<<<256,256,0,stream>>>(A, WA, h0, sw0, sb0, g0, be0, h1);

    // block 1
    k_ha_part<<<1024,256,0,stream>>>(h1, A, R);
    k_hred<<<65,256,0,stream>>>(R, HA);
    k_coeff<<<256,256,0,stream>>>(HA, Ug, cRe, cIm);
    k_mixed<<<256,256,0,stream>>>(cRe, cIm, wr1, wi1, mRe, mIm);
    k_wa<<<65,256,0,stream>>>(mRe, mIm, Ug, WA);
    k_yfuse<<<256,256,0,stream>>>(A, WA, h1, sw1, sb1, g1, be1, h0);

    k_proj<<<256,256,0,stream>>>(h0, pw, pb, out);
}

// Round 5
// 2408.113 us; speedup vs baseline: 1.6505x; 1.6505x over previous
//
#include <hip/hip_runtime.h>

#define B_   4
#define P_   16384
#define HID_ 64
#define M_   256
#define J_   65   // 64 features + constant

__device__ __forceinline__ float gelu_f(float x){
    return 0.5f * x * (1.0f + erff(x * 0.70710678118654752440f));
}

// ---------------- lift: h0[b][o][p] = lift_w[o]·[x0,x1,x2,gh,gw] + lift_b[o] ----------------
__global__ __launch_bounds__(256) void k_lift(const float* __restrict__ x,
        const float* __restrict__ lw, const float* __restrict__ lb,
        float* __restrict__ h0){
    __shared__ float lwl[320];
    __shared__ float lbl[64];
    int tid = threadIdx.x;
    for (int i = tid; i < 320; i += 256) lwl[i] = lw[i];
    if (tid < 64)  lbl[tid] = lb[tid];
    __syncthreads();
    int t = blockIdx.x*256 + tid;
    int b = t >> 14, p = t & (P_-1);
    float gh = (float)(p >> 7) * (1.0f/127.0f);
    float gw = (float)(p & 127) * (1.0f/127.0f);
    const float* xb = x + (size_t)b*3*P_ + p;
    float x0 = xb[0], x1 = xb[P_], x2 = xb[2*P_];
    float* hb = h0 + (size_t)b*64*P_ + p;
    #pragma unroll
    for (int o = 0; o < 64; ++o){
        const float* w = lwl + o*5;
        float v = lbl[o] + w[0]*x0 + w[1]*x1 + w[2]*x2 + w[3]*gh + w[4]*gw;
        hb[(size_t)o*P_] = v;
    }
}

// ---------------- per-pixel MLP: A[b][p][j] = gelu(gelu([gh,gw,h]·w0+b0)·w1+b1) ----------------
__global__ __launch_bounds__(256) void k_mlp(const float* __restrict__ h0,
        const float* __restrict__ w0, const float* __restrict__ b0,
        const float* __restrict__ w1, const float* __restrict__ b1,
        float* __restrict__ A){
    __shared__ float wl[4288];
    int tid = threadIdx.x;
    int t = blockIdx.x*256 + tid;
    int b = t >> 14, p = t & (P_-1);
    for (int i = tid; i < 4224; i += 256) wl[i] = w0[i];
    if (tid < 64) wl[4224+tid] = b0[tid];
    __syncthreads();
    float gh = (float)(p >> 7)*(1.0f/127.0f), gw = (float)(p & 127)*(1.0f/127.0f);
    float z0[64];
    #pragma unroll
    for (int j = 0; j < 64; ++j) z0[j] = wl[4224+j];
    {
        const float4* wa = (const float4*)(wl);
        const float4* wb = (const float4*)(wl + 64);
        #pragma unroll
        for (int j4 = 0; j4 < 16; ++j4){
            float4 a = wa[j4], c = wb[j4];
            z0[j4*4+0] += gh*a.x + gw*c.x;
            z0[j4*4+1] += gh*a.y + gw*c.y;
            z0[j4*4+2] += gh*a.z + gw*c.z;
            z0[j4*4+3] += gh*a.w + gw*c.w;
        }
    }
    const float* hb = h0 + (size_t)b*64*P_ + p;
    #pragma unroll 1
    for (int c = 2; c < 66; ++c){
        float v = hb[(size_t)(c-2)*P_];
        const float4* wr = (const float4*)(wl + c*64);
        #pragma unroll
        for (int j4 = 0; j4 < 16; ++j4){
            float4 w = wr[j4];
            z0[j4*4+0] += v*w.x; z0[j4*4+1] += v*w.y;
            z0[j4*4+2] += v*w.z; z0[j4*4+3] += v*w.w;
        }
    }
    #pragma unroll
    for (int j = 0; j < 64; ++j) z0[j] = gelu_f(z0[j]);
    __syncthreads();
    for (int i = tid; i < 4096; i += 256) wl[i] = w1[i];
    if (tid < 64) wl[4096+tid] = b1[tid];
    __syncthreads();
    float z1[64];
    #pragma unroll
    for (int j = 0; j < 64; ++j) z1[j] = wl[4096+j];
    #pragma unroll
    for (int c = 0; c < 64; ++c){
        float v = z0[c];
        const float4* wr = (const float4*)(wl + c*64);
        #pragma unroll
        for (int j4 = 0; j4 < 16; ++j4){
            float4 w = wr[j4];
            z1[j4*4+0] += v*w.x; z1[j4*4+1] += v*w.y;
            z1[j4*4+2] += v*w.z; z1[j4*4+3] += v*w.w;
        }
    }
    float4* Ao = (float4*)(A + ((size_t)b*P_ + p)*64);
    #pragma unroll
    for (int j4 = 0; j4 < 16; ++j4){
        float4 o4;
        o4.x = gelu_f(z1[j4*4+0]); o4.y = gelu_f(z1[j4*4+1]);
        o4.z = gelu_f(z1[j4*4+2]); o4.w = gelu_f(z1[j4*4+3]);
        Ao[j4] = o4;
    }
}

// ---------------- S partials: per 128-pixel chunk, Sp[blk][i*65+j] = sum_q A65[q][i]A65[q][j] ----------------
__global__ __launch_bounds__(256) void k_sgram_part(const float* __restrict__ A, float* __restrict__ Sp){
    __shared__ float At[128*66];
    int tid = threadIdx.x;
    int b  = blockIdx.x >> 7;
    int p0 = (blockIdx.x & 127) << 7;
    for (int idx = tid; idx < 8192; idx += 256){
        int q = idx >> 6, j = idx & 63;
        At[q*66+j] = A[((size_t)b*P_ + p0 + q)*64 + j];
    }
    if (tid < 128) At[tid*66+64] = 1.0f;
    __syncthreads();
    float* outp = Sp + (size_t)blockIdx.x*4225;
    for (int pi = tid; pi < 4225; pi += 256){
        int i = pi / 65, j = pi % 65;
        float s = 0.f;
        for (int q = 0; q < 128; ++q) s += At[q*66+i]*At[q*66+j];
        outp[pi] = s;
    }
}

// ---------------- k_chol: f64 reduce of S partials + in-place f64 Cholesky; writes L as f32 ----------------
__global__ __launch_bounds__(256) void k_chol(const float* __restrict__ Sp, float* __restrict__ Lfg){
    __shared__ double Sl[4225];
    __shared__ double invd[65];
    int b = blockIdx.x, tid = threadIdx.x;
    for (int e = tid; e < 4225; e += 256){
        double a = 0.0;
        const float* sp = Sp + (size_t)b*128*4225 + e;
        for (int c = 0; c < 128; ++c) a += (double)sp[(size_t)c*4225];
        Sl[e] = a;
    }
    __syncthreads();
    double S00 = Sl[0];
    // owned lower-triangle elements (i>=j), 2145 total, <=9 per thread
    int iiA[9], jjA[9];
    #pragma unroll
    for (int s = 0; s < 9; ++s){
        int e = tid + s*256;
        int i = -1, j = -1;
        if (e < 2145){
            i = (int)((sqrtf(8.0f*(float)e + 1.0f) - 1.0f)*0.5f);
            while ((i+1)*(i+2)/2 <= e) ++i;
            while (i*(i+1)/2 > e) --i;
            j = e - i*(i+1)/2;
        }
        iiA[s] = i; jjA[s] = j;
    }
    for (int k = 0; k < 65; ++k){
        if (tid == 0){
            double piv = Sl[k*65+k];
            double flr = 1e-14 * S00;
            if (!(piv > flr)) piv = flr;
            double l = sqrt(piv);
            Sl[k*65+k] = l;
            invd[k] = 1.0/l;
        }
        __syncthreads();
        { int i = k+1+tid; if (i < 65) Sl[i*65+k] *= invd[k]; }
        __syncthreads();
        #pragma unroll
        for (int s = 0; s < 9; ++s){
            int i = iiA[s], j = jjA[s];
            if (j > k) Sl[i*65+j] -= Sl[i*65+k]*Sl[j*65+k];
        }
        __syncthreads();
    }
    for (int e = tid; e < 4225; e += 256) Lfg[b*4225+e] = (float)Sl[e];
}

// ---------------- k_mgs v2: f32 MGS on d=L^T c; published column as packed float4 broadcasts ----------------
// LDS: Lf 4225 + invdf 65 + ck4 33*4  ~= 17.7 KB
__global__ __launch_bounds__(256, 1) void k_mgs(const float* __restrict__ Lfg,
        const float* __restrict__ wf, const float* __restrict__ bf,
        float2* __restrict__ Ug){
    __shared__ float Lf[4225];
    __shared__ float invdf[65];
    __shared__ float4 ck4[33];
    int b = blockIdx.x, tid = threadIdx.x, m = tid;
    for (int i = tid; i < 4225; i += 256) Lf[i] = Lfg[b*4225+i];
    __syncthreads();
    if (tid < 65) invdf[tid] = 1.0f / Lf[tid*66];
    // d_m = L^T c_m  (c streamed from global)
    float dr[65], di[65];
    #pragma unroll
    for (int i = 0; i < 65; ++i){ dr[i] = 0.f; di[i] = 0.f; }
    #pragma unroll
    for (int j = 0; j < 65; ++j){
        float cjr, cji;
        if (j < 64){ cjr = wf[j*512 + m]; cji = wf[j*512 + 256 + m]; }
        else       { cjr = bf[m];         cji = bf[256 + m]; }
        #pragma unroll
        for (int i = 0; i <= j; ++i){
            float l = Lf[j*65+i];
            dr[i] += l*cjr; di[i] += l*cji;
        }
    }
    __syncthreads();
    // MGS over 256 columns in 65-dim space (reference semantics incl. +1e-8)
    for (int k = 0; k < 256; ++k){
        if (tid == k){
            #pragma unroll
            for (int jj = 0; jj < 32; ++jj)
                ck4[jj] = make_float4(dr[2*jj], di[2*jj], dr[2*jj+1], di[2*jj+1]);
            ck4[32] = make_float4(dr[64], di[64], 0.f, 0.f);
        }
        __syncthreads();
        float nrm = 0.f, pr = 0.f, pi2 = 0.f;
        if (m >= k){
            #pragma unroll
            for (int jj = 0; jj < 32; ++jj){
                float4 v = ck4[jj];
                nrm += v.x*v.x + v.y*v.y + v.z*v.z + v.w*v.w;
                pr  += v.x*dr[2*jj] + v.y*di[2*jj] + v.z*dr[2*jj+1] + v.w*di[2*jj+1];
                pi2 += v.x*di[2*jj] - v.y*dr[2*jj] + v.z*di[2*jj+1] - v.w*dr[2*jj+1];
            }
            float4 v = ck4[32];
            nrm += v.x*v.x + v.y*v.y;
            pr  += v.x*dr[64] + v.y*di[64];
            pi2 += v.x*di[64] - v.y*dr[64];
        }
        float inv = 1.0f/(sqrtf(nrm) + 1e-8f);
        if (m > k){
            float ar = inv*inv*pr, ai = inv*inv*pi2;
            #pragma unroll
            for (int jj = 0; jj < 32; ++jj){
                float4 v = ck4[jj];
                dr[2*jj]   -= v.x*ar - v.y*ai;
                di[2*jj]   -= v.x*ai + v.y*ar;
                dr[2*jj+1] -= v.z*ar - v.w*ai;
                di[2*jj+1] -= v.z*ai + v.w*ar;
            }
            float4 v = ck4[32];
            dr[64] -= v.x*ar - v.y*ai;
            di[64] -= v.x*ai + v.y*ar;
        } else if (m == k){
            #pragma unroll
            for (int j = 0; j < 65; ++j){ dr[j] *= inv; di[j] *= inv; }
        }
        __syncthreads();
    }
    // back-substitution: solve L^T u = d in place
    #pragma unroll
    for (int j = 64; j >= 0; --j){
        float idj = invdf[j];
        float ujr = dr[j]*idj, uji = di[j]*idj;
        dr[j] = ujr; di[j] = uji;
        #pragma unroll
        for (int i = 0; i < j; ++i){
            float l = Lf[j*65+i];
            dr[i] -= l*ujr; di[i] -= l*uji;
        }
    }
    #pragma unroll
    for (int j = 0; j < 65; ++j)
        Ug[b*16640 + (j<<8) + m] = make_float2(dr[j], di[j]);
}

// ---------------- HA partials: 64-pixel chunks, HAp[blk][c*65+j] ----------------
__global__ __launch_bounds__(256) void k_ha_part(const float* __restrict__ h,
        const float* __restrict__ A, float* __restrict__ HAp){
    __shared__ float htl[64*65];
    __shared__ float Atl[64*66];
    int tid = threadIdx.x;
    int b  = blockIdx.x >> 8;
    int p0 = (blockIdx.x & 255) << 6;
    for (int idx = tid; idx < 4096; idx += 256){
        int c = idx >> 6, q = idx & 63;
        htl[c*65+q] = h[((size_t)b*64 + c)*P_ + p0 + q];
    }
    for (int idx = tid; idx < 4096; idx += 256){
        int q = idx >> 6, j = idx & 63;
        Atl[q*66+j] = A[((size_t)b*P_ + p0 + q)*64 + j];
    }
    if (tid < 64) Atl[tid*66+64] = 1.0f;
    __syncthreads();
    float* outp = HAp + (size_t)blockIdx.x*4160;
    for (int pi = tid; pi < 4160; pi += 256){
        int c = pi / 65, j = pi % 65;
        float s = 0.f;
        for (int q = 0; q < 64; ++q) s += htl[c*65+q]*Atl[q*66+j];
        outp[pi] = s;
    }
}

// ---------------- HA reduce: 256 partials ----------------
__global__ __launch_bounds__(256) void k_hred(const float* __restrict__ HAp, float* __restrict__ HA){
    int t = blockIdx.x*256 + threadIdx.x;
    if (t >= B_*4160) return;
    int b = t / 4160, e = t - b*4160;
    const float* hp = HAp + (size_t)b*256*4160 + e;
    double acc = 0.0;
    for (int c = 0; c < 256; ++c) acc += (double)hp[(size_t)c*4160];
    HA[t] = (float)acc;
}

// ---------------- coeff = HA · conj(U) / P ----------------
__global__ __launch_bounds__(256) void k_coeff(const float* __restrict__ HA,
        const float2* __restrict__ Ug,
        float* __restrict__ cRe, float* __restrict__ cIm){
    int t = blockIdx.x*256 + threadIdx.x;
    int b = t >> 14, c = (t >> 8) & 63, m = t & 255;
    const float*  ha = HA + b*4160 + c*65;
    const float2* u  = Ug + b*16640 + m;
    float sr = 0.f, si = 0.f;
    for (int j = 0; j < 65; ++j){
        float hv = ha[j];
        float2 uv = u[j<<8];
        sr += hv*uv.x; si += hv*uv.y;
    }
    cRe[t] =  sr * (1.0f/16384.0f);
    cIm[t] = -si * (1.0f/16384.0f);
}

// ---------------- mixed[b,o,m] = sum_c coeff[b,c,m] * (wr + i wi) ----------------
__global__ __launch_bounds__(256) void k_mixed(const float* __restrict__ cRe, const float* __restrict__ cIm,
        const float* __restrict__ wr, const float* __restrict__ wi,
        float* __restrict__ mRe, float* __restrict__ mIm){
    int t = blockIdx.x*256 + threadIdx.x;
    int b = t >> 14, o = (t >> 8) & 63, m = t & 255;
    const float* cr  = cRe + b*16384 + m;
    const float* ci  = cIm + b*16384 + m;
    const float* wrp = wr + o*256 + m;
    const float* wip = wi + o*256 + m;
    float ar = 0.f, ai = 0.f;
    for (int c = 0; c < 64; ++c){
        float crv = cr[c<<8], civ = ci[c<<8];
        float wrv = wrp[(size_t)c<<14], wiv = wip[(size_t)c<<14];
        ar += crv*wrv - civ*wiv;
        ai += crv*wiv + civ*wrv;
    }
    mRe[t] = ar; mIm[t] = ai;
}

// ---------------- WA[o][j] = Re( sum_m mixed[o,m] * U[j,m] ) ----------------
__global__ __launch_bounds__(256) void k_wa(const float* __restrict__ mRe, const float* __restrict__ mIm,
        const float2* __restrict__ Ug, float* __restrict__ WA){
    int t = blockIdx.x*256 + threadIdx.x;
    if (t >= B_*4160) return;
    int b = t / 4160;
    int r = t - b*4160;
    int o = r / 65, j = r % 65;
    const float*  mr = mRe + b*16384 + o*256;
    const float*  mi = mIm + b*16384 + o*256;
    const float2* u  = Ug + b*16640 + (j<<8);
    float s = 0.f;
    for (int m = 0; m < 256; ++m){
        float2 uv = u[m];
        s += mr[m]*uv.x - mi[m]*uv.y;
    }
    WA[t] = s;
}

// ---------------- y = WA·A65^T ; z = y + skip(h) ; LN ; GELU ----------------
__global__ __launch_bounds__(256) void k_yfuse(const float* __restrict__ A,
        const float* __restrict__ WAg, const float* __restrict__ hin,
        const float* __restrict__ sw, const float* __restrict__ sb,
        const float* __restrict__ gam, const float* __restrict__ bet,
        float* __restrict__ hout){
    __shared__ float WAt[4096];   // [j][o]
    __shared__ float swT[4096];   // [c][o]
    __shared__ float WAc[64], sbl[64], gl[64], bl[64];
    int tid = threadIdx.x;
    int b = blockIdx.x >> 6;
    int p = ((blockIdx.x & 63) << 8) + tid;
    const float* wab = WAg + b*4160;
    for (int idx = tid; idx < 4096; idx += 256){
        int j = idx >> 6, o = idx & 63;
        WAt[idx] = wab[o*65 + j];
        swT[idx] = sw[o*64 + j];
    }
    if (tid < 64){ WAc[tid] = wab[tid*65+64]; sbl[tid] = sb[tid]; gl[tid] = gam[tid]; bl[tid] = bet[tid]; }
    __syncthreads();
    float acc[64];
    #pragma unroll
    for (int o = 0; o < 64; ++o) acc[o] = 0.f;
    const float4* Ar = (const float4*)(A + ((size_t)b*P_ + p)*64);
    #pragma unroll 1
    for (int j4 = 0; j4 < 16; ++j4){
        float4 av = Ar[j4];
        const float* w0p = WAt + (j4*4+0)*64;
        const float* w1p = WAt + (j4*4+1)*64;
        const float* w2p = WAt + (j4*4+2)*64;
        const float* w3p = WAt + (j4*4+3)*64;
        #pragma unroll
        for (int o = 0; o < 64; ++o)
            acc[o] += av.x*w0p[o] + av.y*w1p[o] + av.z*w2p[o] + av.w*w3p[o];
    }
    #pragma unroll 1
    for (int c = 0; c < 64; ++c){
        float hv = hin[((size_t)b*64+c)*P_ + p];
        const float* wrow = swT + c*64;
        #pragma unroll
        for (int o = 0; o < 64; ++o) acc[o] += hv*wrow[o];
    }
    float mu = 0.f;
    #pragma unroll
    for (int o = 0; o < 64; ++o){ acc[o] += WAc[o] + sbl[o]; mu += acc[o]; }
    mu *= (1.0f/64.0f);
    float var = 0.f;
    #pragma unroll
    for (int o = 0; o < 64; ++o){ float d = acc[o]-mu; var += d*d; }
    var *= (1.0f/64.0f);
    float rs = 1.0f/sqrtf(var + 1e-6f);
    float* hb = hout + (size_t)b*64*P_ + p;
    #pragma unroll
    for (int o = 0; o < 64; ++o){
        float zn = (acc[o]-mu)*rs*gl[o] + bl[o];
        hb[(size_t)o*P_] = gelu_f(zn);
    }
}

// ---------------- final projection ----------------
__global__ __launch_bounds__(256) void k_proj(const float* __restrict__ h,
        const float* __restrict__ pw, const float* __restrict__ pb,
        float* __restrict__ out){
    int t = blockIdx.x*256 + threadIdx.x;
    int b = t >> 14, p = t & (P_-1);
    const float* hb = h + (size_t)b*64*P_ + p;
    float s = pb[0];
    for (int c = 0; c < 64; ++c) s += pw[c]*hb[(size_t)c*P_];
    out[t] = s;
}

extern "C" void kernel_launch(void* const* d_in, const int* in_sizes, int n_in,
                              void* d_out, int out_size, void* d_ws, size_t ws_size,
                              hipStream_t stream){
    const float* x      = (const float*)d_in[0];
    const float* lift_w = (const float*)d_in[1];
    const float* lift_b = (const float*)d_in[2];
    const float* w0     = (const float*)d_in[3];
    const float* b0     = (const float*)d_in[4];
    const float* w1     = (const float*)d_in[5];
    const float* b1     = (const float*)d_in[6];
    const float* wf     = (const float*)d_in[7];
    const float* bf     = (const float*)d_in[8];
    const float* wr0 = (const float*)d_in[9];
    const float* wi0 = (const float*)d_in[10];
    const float* sw0 = (const float*)d_in[11];
    const float* sb0 = (const float*)d_in[12];
    const float* g0  = (const float*)d_in[13];
    const float* be0 = (const float*)d_in[14];
    const float* wr1 = (const float*)d_in[15];
    const float* wi1 = (const float*)d_in[16];
    const float* sw1 = (const float*)d_in[17];
    const float* sb1 = (const float*)d_in[18];
    const float* g1  = (const float*)d_in[19];
    const float* be1 = (const float*)d_in[20];
    const float* pw  = (const float*)d_in[21];
    const float* pb  = (const float*)d_in[22];
    float* out = (float*)d_out;
    float* ws = (float*)d_ws;

    float*  h0  = ws;                        // 4,194,304 f
    float*  h1  = ws + 4194304;              // 4,194,304 f
    float*  A   = ws + 8388608;              // 4,194,304 f
    float*  R   = ws + 12582912;             // union: Sp (512*4225) / HAp (1024*4160) = 4,259,840 f
    float*  Lfg = ws + 16842752;             // 16,900 f
    float*  HA  = ws + 16859652;             // 16,640 f
    float2* Ug  = (float2*)(ws + 16876292);  // 16,640 float2 (float offset even -> 8B aligned)
    float*  cRe = ws + 16909572;             // 65,536 f
    float*  cIm = ws + 16975108;
    float*  mRe = ws + 17040644;
    float*  mIm = ws + 17106180;
    float*  WA  = ws + 17171716;             // 16,640 f -> end 17,188,356 f (~68.8 MB)
    (void)ws_size; (void)in_sizes; (void)n_in; (void)out_size;

    k_lift<<<256,256,0,stream>>>(x, lift_w, lift_b, h0);
    k_mlp<<<256,256,0,stream>>>(h0, w0, b0, w1, b1, A);
    k_sgram_part<<<512,256,0,stream>>>(A, R);
    k_chol<<<4,256,0,stream>>>(R, Lfg);
    k_mgs<<<4,256,0,stream>>>(Lfg, wf, bf, Ug);

    // block 0
    k_ha_part<<<1024,256,0,stream>>>(h0, A, R);
    k_hred<<<65,256,0,stream>>>(R, HA);
    k_coeff<<<256,256,0,stream>>>(HA, Ug, cRe, cIm);
    k_mixed<<<256,256,0,stream>>>(cRe, cIm, wr0, wi0, mRe, mIm);
    k_wa<<<65,256,0,stream>>>(mRe, mIm, Ug, WA);
    k_yfuse<<<256,256,0,stream>>>(A, WA, h0, sw0, sb0, g0, be0, h1);

    // block 1
    k_ha_part<<<1024,256,0,stream>>>(h1, A, R);
    k_hred<<<65,256,0,stream>>>(R, HA);
    k_coeff<<<256,256,0,stream>>>(HA, Ug, cRe, cIm);
    k_mixed<<<256,256,0,stream>>>(cRe, cIm, wr1, wi1, mRe, mIm);
    k_wa<<<65,256,0,stream>>>(mRe, mIm, Ug, WA);
    k_yfuse<<<256,256,0,stream>>>(A, WA, h1, sw1, sb1, g1, be1, h0);

    k_proj<<<256,256,0,stream>>>(h0, pw, pb, out);
}

// Round 8
// 2143.082 us; speedup vs baseline: 1.8546x; 1.1237x over previous
//
#include <hip/hip_runtime.h>

#define B_   4
#define P_   16384
#define HID_ 64
#define M_   256
#define J_   65   // 64 features + constant

__device__ __forceinline__ float gelu_f(float x){
    return 0.5f * x * (1.0f + erff(x * 0.70710678118654752440f));
}

// ---------------- lift: h0[b][o][p] ----------------
__global__ __launch_bounds__(256) void k_lift(const float* __restrict__ x,
        const float* __restrict__ lw, const float* __restrict__ lb,
        float* __restrict__ h0){
    __shared__ float lwl[320];
    __shared__ float lbl[64];
    int tid = threadIdx.x;
    for (int i = tid; i < 320; i += 256) lwl[i] = lw[i];
    if (tid < 64)  lbl[tid] = lb[tid];
    __syncthreads();
    int t = blockIdx.x*256 + tid;
    int b = t >> 14, p = t & (P_-1);
    float gh = (float)(p >> 7) * (1.0f/127.0f);
    float gw = (float)(p & 127) * (1.0f/127.0f);
    const float* xb = x + (size_t)b*3*P_ + p;
    float x0 = xb[0], x1 = xb[P_], x2 = xb[2*P_];
    float* hb = h0 + (size_t)b*64*P_ + p;
    #pragma unroll
    for (int o = 0; o < 64; ++o){
        const float* w = lwl + o*5;
        float v = lbl[o] + w[0]*x0 + w[1]*x1 + w[2]*x2 + w[3]*gh + w[4]*gw;
        hb[(size_t)o*P_] = v;
    }
}

// ---------------- per-pixel MLP -> A stored FEATURE-MAJOR A[b][j][p] ----------------
__global__ __launch_bounds__(256) void k_mlp(const float* __restrict__ h0,
        const float* __restrict__ w0, const float* __restrict__ b0,
        const float* __restrict__ w1, const float* __restrict__ b1,
        float* __restrict__ A){
    __shared__ float wl[4288];
    int tid = threadIdx.x;
    int t = blockIdx.x*256 + tid;
    int b = t >> 14, p = t & (P_-1);
    for (int i = tid; i < 4224; i += 256) wl[i] = w0[i];
    if (tid < 64) wl[4224+tid] = b0[tid];
    __syncthreads();
    float gh = (float)(p >> 7)*(1.0f/127.0f), gw = (float)(p & 127)*(1.0f/127.0f);
    float z0[64];
    #pragma unroll
    for (int j = 0; j < 64; ++j) z0[j] = wl[4224+j];
    {
        const float4* wa = (const float4*)(wl);
        const float4* wb = (const float4*)(wl + 64);
        #pragma unroll
        for (int j4 = 0; j4 < 16; ++j4){
            float4 a = wa[j4], c = wb[j4];
            z0[j4*4+0] += gh*a.x + gw*c.x;
            z0[j4*4+1] += gh*a.y + gw*c.y;
            z0[j4*4+2] += gh*a.z + gw*c.z;
            z0[j4*4+3] += gh*a.w + gw*c.w;
        }
    }
    const float* hb = h0 + (size_t)b*64*P_ + p;
    #pragma unroll 1
    for (int c = 2; c < 66; ++c){
        float v = hb[(size_t)(c-2)*P_];
        const float4* wr = (const float4*)(wl + c*64);
        #pragma unroll
        for (int j4 = 0; j4 < 16; ++j4){
            float4 w = wr[j4];
            z0[j4*4+0] += v*w.x; z0[j4*4+1] += v*w.y;
            z0[j4*4+2] += v*w.z; z0[j4*4+3] += v*w.w;
        }
    }
    #pragma unroll
    for (int j = 0; j < 64; ++j) z0[j] = gelu_f(z0[j]);
    __syncthreads();
    for (int i = tid; i < 4096; i += 256) wl[i] = w1[i];
    if (tid < 64) wl[4096+tid] = b1[tid];
    __syncthreads();
    float z1[64];
    #pragma unroll
    for (int j = 0; j < 64; ++j) z1[j] = wl[4096+j];
    #pragma unroll
    for (int c = 0; c < 64; ++c){
        float v = z0[c];
        const float4* wr = (const float4*)(wl + c*64);
        #pragma unroll
        for (int j4 = 0; j4 < 16; ++j4){
            float4 w = wr[j4];
            z1[j4*4+0] += v*w.x; z1[j4*4+1] += v*w.y;
            z1[j4*4+2] += v*w.z; z1[j4*4+3] += v*w.w;
        }
    }
    float* Ab = A + (size_t)b*64*P_ + p;
    #pragma unroll
    for (int j = 0; j < 64; ++j)
        Ab[(size_t)j*P_] = gelu_f(z1[j]);   // coalesced scalar stores
}

// ---------------- S partials: A [b][j][p]; transpose into LDS at load ----------------
__global__ __launch_bounds__(256) void k_sgram_part(const float* __restrict__ A, float* __restrict__ Sp){
    __shared__ float At[128*66];   // [q][j]
    int tid = threadIdx.x;
    int b  = blockIdx.x >> 7;
    int p0 = (blockIdx.x & 127) << 7;
    for (int idx = tid; idx < 8192; idx += 256){
        int j = idx >> 7, q = idx & 127;           // global coalesced over q
        At[q*66+j] = A[((size_t)b*64 + j)*P_ + p0 + q];
    }
    if (tid < 128) At[tid*66+64] = 1.0f;
    __syncthreads();
    float* outp = Sp + (size_t)blockIdx.x*4225;
    for (int pi = tid; pi < 4225; pi += 256){
        int i = pi / 65, j = pi % 65;
        float s = 0.f;
        for (int q = 0; q < 128; ++q) s += At[q*66+i]*At[q*66+j];
        outp[pi] = s;
    }
}

// ---------------- k_chol: f64 reduce + f64 Cholesky; store L (f32), upper zeroed ----------------
__global__ __launch_bounds__(256) void k_chol(const float* __restrict__ Sp, float* __restrict__ Lfg){
    __shared__ double Sl[4225];
    __shared__ double invd[65];
    int b = blockIdx.x, tid = threadIdx.x;
    for (int e = tid; e < 4225; e += 256){
        double a = 0.0;
        const float* sp = Sp + (size_t)b*128*4225 + e;
        for (int c = 0; c < 128; ++c) a += (double)sp[(size_t)c*4225];
        Sl[e] = a;
    }
    __syncthreads();
    double S00 = Sl[0];
    int iiA[9], jjA[9];
    #pragma unroll
    for (int s = 0; s < 9; ++s){
        int e = tid + s*256;
        int i = -1, j = -1;
        if (e < 2145){
            i = (int)((sqrtf(8.0f*(float)e + 1.0f) - 1.0f)*0.5f);
            while ((i+1)*(i+2)/2 <= e) ++i;
            while (i*(i+1)/2 > e) --i;
            j = e - i*(i+1)/2;
        }
        iiA[s] = i; jjA[s] = j;
    }
    for (int k = 0; k < 65; ++k){
        if (tid == 0){
            double piv = Sl[k*65+k];
            double flr = 1e-14 * S00;
            if (!(piv > flr)) piv = flr;
            double l = sqrt(piv);
            Sl[k*65+k] = l;
            invd[k] = 1.0/l;
        }
        __syncthreads();
        { int i = k+1+tid; if (i < 65) Sl[i*65+k] *= invd[k]; }
        __syncthreads();
        #pragma unroll
        for (int s = 0; s < 9; ++s){
            int i = iiA[s], j = jjA[s];
            if (j > k) Sl[i*65+j] -= Sl[i*65+k]*Sl[j*65+k];
        }
        __syncthreads();
    }
    for (int e = tid; e < 4225; e += 256){
        int r_ = e / 65, c_ = e % 65;
        Lfg[b*4225+e] = (c_ <= r_) ? (float)Sl[e] : 0.0f;
    }
}

// ---------------- k_mgs v3: 1024 threads, 4 threads/column; ONE barrier per step ----------------
__global__ __launch_bounds__(1024, 1) void k_mgs(const float* __restrict__ Lfg,
        const float* __restrict__ wf, const float* __restrict__ bf,
        float2* __restrict__ Ug){
    __shared__ float Lf[4225];
    __shared__ float invdf[65];
    __shared__ float2 ckbuf[2][4][17];
    int b = blockIdx.x, tid = threadIdx.x;
    int m = tid >> 2, q = tid & 3;      // column m, quarter q
    int i0 = q << 4;
    for (int i = tid; i < 4225; i += 1024) Lf[i] = Lfg[b*4225+i];
    __syncthreads();
    if (tid < 65) invdf[tid] = 1.0f / Lf[tid*66];
    // d = L^T c (own quarter rows); upper of Lf is zero -> no guards
    float dr[17], di[17];
    #pragma unroll
    for (int r = 0; r < 17; ++r){ dr[r] = 0.f; di[r] = 0.f; }
    #pragma unroll 1
    for (int j = 0; j < 65; ++j){
        float cjr, cji;
        if (j < 64){ cjr = wf[j*512 + m]; cji = wf[j*512 + 256 + m]; }
        else       { cjr = bf[m];         cji = bf[256 + m]; }
        const float* Lrow = Lf + j*65 + i0;
        #pragma unroll
        for (int r = 0; r < 16; ++r){
            float l = Lrow[r];
            dr[r] += l*cjr; di[r] += l*cji;
        }
        if (q == 3){ float l = Lf[j*65 + 64]; dr[16] += l*cjr; di[16] += l*cji; }
    }
    __syncthreads();
    // MGS: 256 steps, ONE barrier each (double-buffered publish).
    for (int k = 0; k < 256; ++k){
        float2* ckq = &ckbuf[k & 1][q][0];
        if (m == k){
            #pragma unroll
            for (int r = 0; r < 17; ++r) ckq[r] = make_float2(dr[r], di[r]);
        }
        __syncthreads();
        float nrm = 0.f, pr = 0.f, pi2 = 0.f;
        #pragma unroll
        for (int r = 0; r < 17; ++r){
            float2 v = ckq[r];
            nrm += v.x*v.x + v.y*v.y;
            pr  += v.x*dr[r] + v.y*di[r];
            pi2 += v.x*di[r] - v.y*dr[r];
        }
        nrm += __shfl_xor(nrm, 1); nrm += __shfl_xor(nrm, 2);
        pr  += __shfl_xor(pr , 1); pr  += __shfl_xor(pr , 2);
        pi2 += __shfl_xor(pi2, 1); pi2 += __shfl_xor(pi2, 2);
        float inv = 1.0f/(sqrtf(nrm) + 1e-8f);
        if (m > k){
            float ar = inv*inv*pr, ai = inv*inv*pi2;
            #pragma unroll
            for (int r = 0; r < 17; ++r){
                float2 v = ckq[r];
                dr[r] -= v.x*ar - v.y*ai;
                di[r] -= v.x*ai + v.y*ar;
            }
        } else if (m == k){
            #pragma unroll
            for (int r = 0; r < 17; ++r){ dr[r] *= inv; di[r] *= inv; }
        }
    }
    __syncthreads();
    // back-substitution L^T u = d, quad-cooperative
    int lbase = (tid & 63) & ~3;
    #pragma unroll
    for (int j = 64; j >= 0; --j){
        const int qo = (j >= 48) ? 3 : (j >> 4);
        const int ro = j - qo*16;
        float ujr_own = dr[ro] * invdf[j];
        float uji_own = di[ro] * invdf[j];
        float ujr = __shfl(ujr_own, lbase | qo, 64);
        float uji = __shfl(uji_own, lbase | qo, 64);
        if (q == qo){ dr[ro] = ujr; di[ro] = uji; }
        #pragma unroll
        for (int r = 0; r < 16; ++r){
            int i = i0 + r;
            if (i < j){
                float l = Lf[j*65 + i];
                dr[r] -= l*ujr; di[r] -= l*uji;
            }
        }
    }
    #pragma unroll
    for (int r = 0; r < 17; ++r){
        int i = i0 + r;
        if (r < 16 || q == 3)
            Ug[b*16640 + (i<<8) + m] = make_float2(dr[r], di[r]);
    }
}

// ---------------- HA partials: h [c][p], A [j][p]; transpose A into LDS ----------------
__global__ __launch_bounds__(256) void k_ha_part(const float* __restrict__ h,
        const float* __restrict__ A, float* __restrict__ HAp){
    __shared__ float htl[64*65];
    __shared__ float Atl[64*66];
    int tid = threadIdx.x;
    int b  = blockIdx.x >> 8;
    int p0 = (blockIdx.x & 255) << 6;
    for (int idx = tid; idx < 4096; idx += 256){
        int c = idx >> 6, q = idx & 63;
        htl[c*65+q] = h[((size_t)b*64 + c)*P_ + p0 + q];
    }
    for (int idx = tid; idx < 4096; idx += 256){
        int j = idx >> 6, q = idx & 63;
        Atl[q*66+j] = A[((size_t)b*64 + j)*P_ + p0 + q];
    }
    if (tid < 64) Atl[tid*66+64] = 1.0f;
    __syncthreads();
    float* outp = HAp + (size_t)blockIdx.x*4160;
    for (int pi = tid; pi < 4160; pi += 256){
        int c = pi / 65, j = pi % 65;
        float s = 0.f;
        for (int q = 0; q < 64; ++q) s += htl[c*65+q]*Atl[q*66+j];
        outp[pi] = s;
    }
}

// ---------------- HA reduce ----------------
__global__ __launch_bounds__(256) void k_hred(const float* __restrict__ HAp, float* __restrict__ HA){
    int t = blockIdx.x*256 + threadIdx.x;
    if (t >= B_*4160) return;
    int b = t / 4160, e = t - b*4160;
    const float* hp = HAp + (size_t)b*256*4160 + e;
    double acc = 0.0;
    for (int c = 0; c < 256; ++c) acc += (double)hp[(size_t)c*4160];
    HA[t] = (float)acc;
}

// ---------------- coeff = HA · conj(U) / P ----------------
__global__ __launch_bounds__(256) void k_coeff(const float* __restrict__ HA,
        const float2* __restrict__ Ug,
        float* __restrict__ cRe, float* __restrict__ cIm){
    int t = blockIdx.x*256 + threadIdx.x;
    int b = t >> 14, c = (t >> 8) & 63, m = t & 255;
    const float*  ha = HA + b*4160 + c*65;
    const float2* u  = Ug + b*16640 + m;
    float sr = 0.f, si = 0.f;
    for (int j = 0; j < 65; ++j){
        float hv = ha[j];
        float2 uv = u[j<<8];
        sr += hv*uv.x; si += hv*uv.y;
    }
    cRe[t] =  sr * (1.0f/16384.0f);
    cIm[t] = -si * (1.0f/16384.0f);
}

// ---------------- mixed ----------------
__global__ __launch_bounds__(256) void k_mixed(const float* __restrict__ cRe, const float* __restrict__ cIm,
        const float* __restrict__ wr, const float* __restrict__ wi,
        float* __restrict__ mRe, float* __restrict__ mIm){
    int t = blockIdx.x*256 + threadIdx.x;
    int b = t >> 14, o = (t >> 8) & 63, m = t & 255;
    const float* cr  = cRe + b*16384 + m;
    const float* ci  = cIm + b*16384 + m;
    const float* wrp = wr + o*256 + m;
    const float* wip = wi + o*256 + m;
    float ar = 0.f, ai = 0.f;
    for (int c = 0; c < 64; ++c){
        float crv = cr[c<<8], civ = ci[c<<8];
        float wrv = wrp[(size_t)c<<14], wiv = wip[(size_t)c<<14];
        ar += crv*wrv - civ*wiv;
        ai += crv*wiv + civ*wrv;
    }
    mRe[t] = ar; mIm[t] = ai;
}

// ---------------- WA[o][j] = Re( sum_m mixed[o,m] * U[j,m] ) ----------------
__global__ __launch_bounds__(256) void k_wa(const float* __restrict__ mRe, const float* __restrict__ mIm,
        const float2* __restrict__ Ug, float* __restrict__ WA){
    int t = blockIdx.x*256 + threadIdx.x;
    if (t >= B_*4160) return;
    int b = t / 4160;
    int r = t - b*4160;
    int o = r / 65, j = r % 65;
    const float*  mr = mRe + b*16384 + o*256;
    const float*  mi = mIm + b*16384 + o*256;
    const float2* u  = Ug + b*16640 + (j<<8);
    float s = 0.f;
    for (int m = 0; m < 256; ++m){
        float2 uv = u[m];
        s += mr[m]*uv.x - mi[m]*uv.y;
    }
    WA[t] = s;
}

// ---------------- y = WA·A65^T ; z = y + skip(h) ; LN ; GELU ----------------
__global__ __launch_bounds__(256) void k_yfuse(const float* __restrict__ A,
        const float* __restrict__ WAg, const float* __restrict__ hin,
        const float* __restrict__ sw, const float* __restrict__ sb,
        const float* __restrict__ gam, const float* __restrict__ bet,
        float* __restrict__ hout){
    __shared__ float WAt[4096];   // [j][o]
    __shared__ float swT[4096];   // [c][o]
    __shared__ float WAc[64], sbl[64], gl[64], bl[64];
    int tid = threadIdx.x;
    int b = blockIdx.x >> 6;
    int p = ((blockIdx.x & 63) << 8) + tid;
    const float* wab = WAg + b*4160;
    for (int idx = tid; idx < 4096; idx += 256){
        int j = idx >> 6, o = idx & 63;
        WAt[idx] = wab[o*65 + j];
        swT[idx] = sw[o*64 + j];
    }
    if (tid < 64){ WAc[tid] = wab[tid*65+64]; sbl[tid] = sb[tid]; gl[tid] = gam[tid]; bl[tid] = bet[tid]; }
    __syncthreads();
    float acc[64];
    #pragma unroll
    for (int o = 0; o < 64; ++o) acc[o] = 0.f;
    const float* Ab = A + (size_t)b*64*P_ + p;
    #pragma unroll 1
    for (int j = 0; j < 64; ++j){
        float aj = Ab[(size_t)j*P_];
        const float* wrow = WAt + j*64;
        #pragma unroll
        for (int o = 0; o < 64; ++o) acc[o] += aj*wrow[o];
    }
    #pragma unroll 1
    for (int c = 0; c < 64; ++c){
        float hv = hin[((size_t)b*64+c)*P_ + p];
        const float* wrow = swT + c*64;
        #pragma unroll
        for (int o = 0; o < 64; ++o) acc[o] += hv*wrow[o];
    }
    float mu = 0.f;
    #pragma unroll
    for (int o = 0; o < 64; ++o){ acc[o] += WAc[o] + sbl[o]; mu += acc[o]; }
    mu *= (1.0f/64.0f);
    float var = 0.f;
    #pragma unroll
    for (int o = 0; o < 64; ++o){ float d = acc[o]-mu; var += d*d; }
    var *= (1.0f/64.0f);
    float rs = 1.0f/sqrtf(var + 1e-6f);
    float* hb = hout + (size_t)b*64*P_ + p;
    #pragma unroll
    for (int o = 0; o < 64; ++o){
        float zn = (acc[o]-mu)*rs*gl[o] + bl[o];
        hb[(size_t)o*P_] = gelu_f(zn);
    }
}

// ---------------- final projection ----------------
__global__ __launch_bounds__(256) void k_proj(const float* __restrict__ h,
        const float* __restrict__ pw, const float* __restrict__ pb,
        float* __restrict__ out){
    int t = blockIdx.x*256 + threadIdx.x;
    int b = t >> 14, p = t & (P_-1);
    const float* hb = h + (size_t)b*64*P_ + p;
    float s = pb[0];
    for (int c = 0; c < 64; ++c) s += pw[c]*hb[(size_t)c*P_];
    out[t] = s;
}

extern "C" void kernel_launch(void* const* d_in, const int* in_sizes, int n_in,
                              void* d_out, int out_size, void* d_ws, size_t ws_size,
                              hipStream_t stream){
    const float* x      = (const float*)d_in[0];
    const float* lift_w = (const float*)d_in[1];
    const float* lift_b = (const float*)d_in[2];
    const float* w0     = (const float*)d_in[3];
    const float* b0     = (const float*)d_in[4];
    const float* w1     = (const float*)d_in[5];
    const float* b1     = (const float*)d_in[6];
    const float* wf     = (const float*)d_in[7];
    const float* bf     = (const float*)d_in[8];
    const float* wr0 = (const float*)d_in[9];
    const float* wi0 = (const float*)d_in[10];
    const float* sw0 = (const float*)d_in[11];
    const float* sb0 = (const float*)d_in[12];
    const float* g0  = (const float*)d_in[13];
    const float* be0 = (const float*)d_in[14];
    const float* wr1 = (const float*)d_in[15];
    const float* wi1 = (const float*)d_in[16];
    const float* sw1 = (const float*)d_in[17];
    const float* sb1 = (const float*)d_in[18];
    const float* g1  = (const float*)d_in[19];
    const float* be1 = (const float*)d_in[20];
    const float* pw  = (const float*)d_in[21];
    const float* pb  = (const float*)d_in[22];
    float* out = (float*)d_out;
    float* ws = (float*)d_ws;

    float*  h0  = ws;                        // 4,194,304 f
    float*  h1  = ws + 4194304;              // 4,194,304 f
    float*  A   = ws + 8388608;              // 4,194,304 f  (layout [b][j][p])
    float*  R   = ws + 12582912;             // union: Sp (512*4225) / HAp (1024*4160)
    float*  Lfg = ws + 16842752;             // 16,900 f
    float*  HA  = ws + 16859652;             // 16,640 f
    float2* Ug  = (float2*)(ws + 16876292);  // 16,640 float2
    float*  cRe = ws + 16909572;
    float*  cIm = ws + 16975108;
    float*  mRe = ws + 17040644;
    float*  mIm = ws + 17106180;
    float*  WA  = ws + 17171716;
    (void)ws_size; (void)in_sizes; (void)n_in; (void)out_size;

    k_lift<<<256,256,0,stream>>>(x, lift_w, lift_b, h0);
    k_mlp<<<256,256,0,stream>>>(h0, w0, b0, w1, b1, A);
    k_sgram_part<<<512,256,0,stream>>>(A, R);
    k_chol<<<4,256,0,stream>>>(R, Lfg);
    k_mgs<<<4,1024,0,stream>>>(Lfg, wf, bf, Ug);

    // block 0
    k_ha_part<<<1024,256,0,stream>>>(h0, A, R);
    k_hred<<<65,256,0,stream>>>(R, HA);
    k_coeff<<<256,256,0,stream>>>(HA, Ug, cRe, cIm);
    k_mixed<<<256,256,0,stream>>>(cRe, cIm, wr0, wi0, mRe, mIm);
    k_wa<<<65,256,0,stream>>>(mRe, mIm, Ug, WA);
    k_yfuse<<<256,256,0,stream>>>(A, WA, h0, sw0, sb0, g0, be0, h1);

    // block 1
    k_ha_part<<<1024,256,0,stream>>>(h1, A, R);
    k_hred<<<65,256,0,stream>>>(R, HA);
    k_coeff<<<256,256,0,stream>>>(HA, Ug, cRe, cIm);
    k_mixed<<<256,256,0,stream>>>(cRe, cIm, wr1, wi1, mRe, mIm);
    k_wa<<<65,256,0,stream>>>(mRe, mIm, Ug, WA);
    k_yfuse<<<256,256,0,stream>>>(A, WA, h1, sw1, sb1, g1, be1, h0);

    k_proj<<<256,256,0,stream>>>(h0, pw, pb, out);
}

// Round 9
// 1274.889 us; speedup vs baseline: 3.1176x; 1.6810x over previous
//
#include <hip/hip_runtime.h>

#define B_   4
#define P_   16384
#define HID_ 64
#define M_   256
#define J_   65   // 64 features + constant

__device__ __forceinline__ float gelu_f(float x){
    return 0.5f * x * (1.0f + erff(x * 0.70710678118654752440f));
}

// ---------------- lift: h0[b][o][p] ----------------
__global__ __launch_bounds__(256) void k_lift(const float* __restrict__ x,
        const float* __restrict__ lw, const float* __restrict__ lb,
        float* __restrict__ h0){
    __shared__ float lwl[320];
    __shared__ float lbl[64];
    int tid = threadIdx.x;
    for (int i = tid; i < 320; i += 256) lwl[i] = lw[i];
    if (tid < 64)  lbl[tid] = lb[tid];
    __syncthreads();
    int t = blockIdx.x*256 + tid;
    int b = t >> 14, p = t & (P_-1);
    float gh = (float)(p >> 7) * (1.0f/127.0f);
    float gw = (float)(p & 127) * (1.0f/127.0f);
    const float* xb = x + (size_t)b*3*P_ + p;
    float x0 = xb[0], x1 = xb[P_], x2 = xb[2*P_];
    float* hb = h0 + (size_t)b*64*P_ + p;
    #pragma unroll
    for (int o = 0; o < 64; ++o){
        const float* w = lwl + o*5;
        float v = lbl[o] + w[0]*x0 + w[1]*x1 + w[2]*x2 + w[3]*gh + w[4]*gw;
        hb[(size_t)o*P_] = v;
    }
}

// ---------------- MLP stage 0: Z0[b][j][p] = gelu([gh,gw,h]·W0 + b0); 64-reg accumulator ----------------
__global__ __launch_bounds__(256) void k_mlp0(const float* __restrict__ h0,
        const float* __restrict__ w0, const float* __restrict__ b0,
        float* __restrict__ Z0){
    __shared__ float wl[4288];   // 66x64 + bias
    int tid = threadIdx.x;
    int t = blockIdx.x*256 + tid;
    int b = t >> 14, p = t & (P_-1);
    for (int i = tid; i < 4224; i += 256) wl[i] = w0[i];
    if (tid < 64) wl[4224+tid] = b0[tid];
    __syncthreads();
    float gh = (float)(p >> 7)*(1.0f/127.0f), gw = (float)(p & 127)*(1.0f/127.0f);
    float acc[64];
    {
        const float4* wa = (const float4*)(wl);        // row 0 (gh)
        const float4* wb = (const float4*)(wl + 64);   // row 1 (gw)
        const float4* bb = (const float4*)(wl + 4224);
        #pragma unroll
        for (int o4 = 0; o4 < 16; ++o4){
            float4 a = wa[o4], c = wb[o4], bs = bb[o4];
            acc[o4*4+0] = bs.x + gh*a.x + gw*c.x;
            acc[o4*4+1] = bs.y + gh*a.y + gw*c.y;
            acc[o4*4+2] = bs.z + gh*a.z + gw*c.z;
            acc[o4*4+3] = bs.w + gh*a.w + gw*c.w;
        }
    }
    const float* hb = h0 + (size_t)b*64*P_ + p;
    #pragma unroll 1
    for (int c = 0; c < 64; ++c){
        float v = hb[(size_t)c*P_];
        const float4* wr = (const float4*)(wl + (c+2)*64);
        #pragma unroll
        for (int o4 = 0; o4 < 16; ++o4){
            float4 w = wr[o4];
            acc[o4*4+0] += v*w.x; acc[o4*4+1] += v*w.y;
            acc[o4*4+2] += v*w.z; acc[o4*4+3] += v*w.w;
        }
    }
    float* zb = Z0 + (size_t)b*64*P_ + p;
    #pragma unroll
    for (int o = 0; o < 64; ++o)
        zb[(size_t)o*P_] = gelu_f(acc[o]);
}

// ---------------- MLP stage 1: A[b][j][p] = gelu(Z0·W1 + b1); 64-reg accumulator ----------------
__global__ __launch_bounds__(256) void k_mlp1(const float* __restrict__ Z0,
        const float* __restrict__ w1, const float* __restrict__ b1,
        float* __restrict__ A){
    __shared__ float wl[4160];   // 64x64 + bias
    int tid = threadIdx.x;
    int t = blockIdx.x*256 + tid;
    int b = t >> 14, p = t & (P_-1);
    for (int i = tid; i < 4096; i += 256) wl[i] = w1[i];
    if (tid < 64) wl[4096+tid] = b1[tid];
    __syncthreads();
    float acc[64];
    {
        const float4* bb = (const float4*)(wl + 4096);
        #pragma unroll
        for (int o4 = 0; o4 < 16; ++o4){
            float4 bs = bb[o4];
            acc[o4*4+0] = bs.x; acc[o4*4+1] = bs.y;
            acc[o4*4+2] = bs.z; acc[o4*4+3] = bs.w;
        }
    }
    const float* zb = Z0 + (size_t)b*64*P_ + p;
    #pragma unroll 1
    for (int c = 0; c < 64; ++c){
        float v = zb[(size_t)c*P_];
        const float4* wr = (const float4*)(wl + c*64);
        #pragma unroll
        for (int o4 = 0; o4 < 16; ++o4){
            float4 w = wr[o4];
            acc[o4*4+0] += v*w.x; acc[o4*4+1] += v*w.y;
            acc[o4*4+2] += v*w.z; acc[o4*4+3] += v*w.w;
        }
    }
    float* Ab = A + (size_t)b*64*P_ + p;
    #pragma unroll
    for (int o = 0; o < 64; ++o)
        Ab[(size_t)o*P_] = gelu_f(acc[o]);
}

// ---------------- S partials: A [b][j][p]; transpose into LDS at load ----------------
__global__ __launch_bounds__(256) void k_sgram_part(const float* __restrict__ A, float* __restrict__ Sp){
    __shared__ float At[128*66];   // [q][j]
    int tid = threadIdx.x;
    int b  = blockIdx.x >> 7;
    int p0 = (blockIdx.x & 127) << 7;
    for (int idx = tid; idx < 8192; idx += 256){
        int j = idx >> 7, q = idx & 127;           // global coalesced over q
        At[q*66+j] = A[((size_t)b*64 + j)*P_ + p0 + q];
    }
    if (tid < 128) At[tid*66+64] = 1.0f;
    __syncthreads();
    float* outp = Sp + (size_t)blockIdx.x*4225;
    for (int pi = tid; pi < 4225; pi += 256){
        int i = pi / 65, j = pi % 65;
        float s = 0.f;
        for (int q = 0; q < 128; ++q) s += At[q*66+i]*At[q*66+j];
        outp[pi] = s;
    }
}

// ---------------- k_chol: f64 reduce + f64 Cholesky; store L (f32), upper zeroed ----------------
__global__ __launch_bounds__(256) void k_chol(const float* __restrict__ Sp, float* __restrict__ Lfg){
    __shared__ double Sl[4225];
    __shared__ double invd[65];
    int b = blockIdx.x, tid = threadIdx.x;
    for (int e = tid; e < 4225; e += 256){
        double a = 0.0;
        const float* sp = Sp + (size_t)b*128*4225 + e;
        for (int c = 0; c < 128; ++c) a += (double)sp[(size_t)c*4225];
        Sl[e] = a;
    }
    __syncthreads();
    double S00 = Sl[0];
    int iiA[9], jjA[9];
    #pragma unroll
    for (int s = 0; s < 9; ++s){
        int e = tid + s*256;
        int i = -1, j = -1;
        if (e < 2145){
            i = (int)((sqrtf(8.0f*(float)e + 1.0f) - 1.0f)*0.5f);
            while ((i+1)*(i+2)/2 <= e) ++i;
            while (i*(i+1)/2 > e) --i;
            j = e - i*(i+1)/2;
        }
        iiA[s] = i; jjA[s] = j;
    }
    for (int k = 0; k < 65; ++k){
        if (tid == 0){
            double piv = Sl[k*65+k];
            double flr = 1e-14 * S00;
            if (!(piv > flr)) piv = flr;
            double l = sqrt(piv);
            Sl[k*65+k] = l;
            invd[k] = 1.0/l;
        }
        __syncthreads();
        { int i = k+1+tid; if (i < 65) Sl[i*65+k] *= invd[k]; }
        __syncthreads();
        #pragma unroll
        for (int s = 0; s < 9; ++s){
            int i = iiA[s], j = jjA[s];
            if (j > k) Sl[i*65+j] -= Sl[i*65+k]*Sl[j*65+k];
        }
        __syncthreads();
    }
    for (int e = tid; e < 4225; e += 256){
        int r_ = e / 65, c_ = e % 65;
        Lfg[b*4225+e] = (c_ <= r_) ? (float)Sl[e] : 0.0f;
    }
}

// ---------------- k_mgs v3: 1024 threads, 4 threads/column; ONE barrier per step ----------------
__global__ __launch_bounds__(1024, 1) void k_mgs(const float* __restrict__ Lfg,
        const float* __restrict__ wf, const float* __restrict__ bf,
        float2* __restrict__ Ug){
    __shared__ float Lf[4225];
    __shared__ float invdf[65];
    __shared__ float2 ckbuf[2][4][17];
    int b = blockIdx.x, tid = threadIdx.x;
    int m = tid >> 2, q = tid & 3;      // column m, quarter q
    int i0 = q << 4;
    for (int i = tid; i < 4225; i += 1024) Lf[i] = Lfg[b*4225+i];
    __syncthreads();
    if (tid < 65) invdf[tid] = 1.0f / Lf[tid*66];
    // d = L^T c (own quarter rows); upper of Lf is zero -> no guards
    float dr[17], di[17];
    #pragma unroll
    for (int r = 0; r < 17; ++r){ dr[r] = 0.f; di[r] = 0.f; }
    #pragma unroll 1
    for (int j = 0; j < 65; ++j){
        float cjr, cji;
        if (j < 64){ cjr = wf[j*512 + m]; cji = wf[j*512 + 256 + m]; }
        else       { cjr = bf[m];         cji = bf[256 + m]; }
        const float* Lrow = Lf + j*65 + i0;
        #pragma unroll
        for (int r = 0; r < 16; ++r){
            float l = Lrow[r];
            dr[r] += l*cjr; di[r] += l*cji;
        }
        if (q == 3){ float l = Lf[j*65 + 64]; dr[16] += l*cjr; di[16] += l*cji; }
    }
    __syncthreads();
    // MGS: 256 steps, ONE barrier each (double-buffered publish).
    for (int k = 0; k < 256; ++k){
        float2* ckq = &ckbuf[k & 1][q][0];
        if (m == k){
            #pragma unroll
            for (int r = 0; r < 17; ++r) ckq[r] = make_float2(dr[r], di[r]);
        }
        __syncthreads();
        float nrm = 0.f, pr = 0.f, pi2 = 0.f;
        #pragma unroll
        for (int r = 0; r < 17; ++r){
            float2 v = ckq[r];
            nrm += v.x*v.x + v.y*v.y;
            pr  += v.x*dr[r] + v.y*di[r];
            pi2 += v.x*di[r] - v.y*dr[r];
        }
        nrm += __shfl_xor(nrm, 1); nrm += __shfl_xor(nrm, 2);
        pr  += __shfl_xor(pr , 1); pr  += __shfl_xor(pr , 2);
        pi2 += __shfl_xor(pi2, 1); pi2 += __shfl_xor(pi2, 2);
        float inv = 1.0f/(sqrtf(nrm) + 1e-8f);
        if (m > k){
            float ar = inv*inv*pr, ai = inv*inv*pi2;
            #pragma unroll
            for (int r = 0; r < 17; ++r){
                float2 v = ckq[r];
                dr[r] -= v.x*ar - v.y*ai;
                di[r] -= v.x*ai + v.y*ar;
            }
        } else if (m == k){
            #pragma unroll
            for (int r = 0; r < 17; ++r){ dr[r] *= inv; di[r] *= inv; }
        }
    }
    __syncthreads();
    // back-substitution L^T u = d, quad-cooperative
    int lbase = (tid & 63) & ~3;
    #pragma unroll
    for (int j = 64; j >= 0; --j){
        const int qo = (j >= 48) ? 3 : (j >> 4);
        const int ro = j - qo*16;
        float ujr_own = dr[ro] * invdf[j];
        float uji_own = di[ro] * invdf[j];
        float ujr = __shfl(ujr_own, lbase | qo, 64);
        float uji = __shfl(uji_own, lbase | qo, 64);
        if (q == qo){ dr[ro] = ujr; di[ro] = uji; }
        #pragma unroll
        for (int r = 0; r < 16; ++r){
            int i = i0 + r;
            if (i < j){
                float l = Lf[j*65 + i];
                dr[r] -= l*ujr; di[r] -= l*uji;
            }
        }
    }
    #pragma unroll
    for (int r = 0; r < 17; ++r){
        int i = i0 + r;
        if (r < 16 || q == 3)
            Ug[b*16640 + (i<<8) + m] = make_float2(dr[r], di[r]);
    }
}

// ---------------- HA partials: h [c][p], A [j][p]; transpose A into LDS ----------------
__global__ __launch_bounds__(256) void k_ha_part(const float* __restrict__ h,
        const float* __restrict__ A, float* __restrict__ HAp){
    __shared__ float htl[64*65];
    __shared__ float Atl[64*66];
    int tid = threadIdx.x;
    int b  = blockIdx.x >> 8;
    int p0 = (blockIdx.x & 255) << 6;
    for (int idx = tid; idx < 4096; idx += 256){
        int c = idx >> 6, q = idx & 63;
        htl[c*65+q] = h[((size_t)b*64 + c)*P_ + p0 + q];
    }
    for (int idx = tid; idx < 4096; idx += 256){
        int j = idx >> 6, q = idx & 63;
        Atl[q*66+j] = A[((size_t)b*64 + j)*P_ + p0 + q];
    }
    if (tid < 64) Atl[tid*66+64] = 1.0f;
    __syncthreads();
    float* outp = HAp + (size_t)blockIdx.x*4160;
    for (int pi = tid; pi < 4160; pi += 256){
        int c = pi / 65, j = pi % 65;
        float s = 0.f;
        for (int q = 0; q < 64; ++q) s += htl[c*65+q]*Atl[q*66+j];
        outp[pi] = s;
    }
}

// ---------------- HA reduce ----------------
__global__ __launch_bounds__(256) void k_hred(const float* __restrict__ HAp, float* __restrict__ HA){
    int t = blockIdx.x*256 + threadIdx.x;
    if (t >= B_*4160) return;
    int b = t / 4160, e = t - b*4160;
    const float* hp = HAp + (size_t)b*256*4160 + e;
    double acc = 0.0;
    for (int c = 0; c < 256; ++c) acc += (double)hp[(size_t)c*4160];
    HA[t] = (float)acc;
}

// ---------------- coeff = HA · conj(U) / P ----------------
__global__ __launch_bounds__(256) void k_coeff(const float* __restrict__ HA,
        const float2* __restrict__ Ug,
        float* __restrict__ cRe, float* __restrict__ cIm){
    int t = blockIdx.x*256 + threadIdx.x;
    int b = t >> 14, c = (t >> 8) & 63, m = t & 255;
    const float*  ha = HA + b*4160 + c*65;
    const float2* u  = Ug + b*16640 + m;
    float sr = 0.f, si = 0.f;
    for (int j = 0; j < 65; ++j){
        float hv = ha[j];
        float2 uv = u[j<<8];
        sr += hv*uv.x; si += hv*uv.y;
    }
    cRe[t] =  sr * (1.0f/16384.0f);
    cIm[t] = -si * (1.0f/16384.0f);
}

// ---------------- mixed ----------------
__global__ __launch_bounds__(256) void k_mixed(const float* __restrict__ cRe, const float* __restrict__ cIm,
        const float* __restrict__ wr, const float* __restrict__ wi,
        float* __restrict__ mRe, float* __restrict__ mIm){
    int t = blockIdx.x*256 + threadIdx.x;
    int b = t >> 14, o = (t >> 8) & 63, m = t & 255;
    const float* cr  = cRe + b*16384 + m;
    const float* ci  = cIm + b*16384 + m;
    const float* wrp = wr + o*256 + m;
    const float* wip = wi + o*256 + m;
    float ar = 0.f, ai = 0.f;
    for (int c = 0; c < 64; ++c){
        float crv = cr[c<<8], civ = ci[c<<8];
        float wrv = wrp[(size_t)c<<14], wiv = wip[(size_t)c<<14];
        ar += crv*wrv - civ*wiv;
        ai += crv*wiv + civ*wrv;
    }
    mRe[t] = ar; mIm[t] = ai;
}

// ---------------- WA[o][j] = Re( sum_m mixed[o,m] * U[j,m] ) ----------------
__global__ __launch_bounds__(256) void k_wa(const float* __restrict__ mRe, const float* __restrict__ mIm,
        const float2* __restrict__ Ug, float* __restrict__ WA){
    int t = blockIdx.x*256 + threadIdx.x;
    if (t >= B_*4160) return;
    int b = t / 4160;
    int r = t - b*4160;
    int o = r / 65, j = r % 65;
    const float*  mr = mRe + b*16384 + o*256;
    const float*  mi = mIm + b*16384 + o*256;
    const float2* u  = Ug + b*16640 + (j<<8);
    float s = 0.f;
    for (int m = 0; m < 256; ++m){
        float2 uv = u[m];
        s += mr[m]*uv.x - mi[m]*uv.y;
    }
    WA[t] = s;
}

// ---------------- y = WA·A65^T ; z = y + skip(h) ; LN ; GELU ----------------
__global__ __launch_bounds__(256) void k_yfuse(const float* __restrict__ A,
        const float* __restrict__ WAg, const float* __restrict__ hin,
        const float* __restrict__ sw, const float* __restrict__ sb,
        const float* __restrict__ gam, const float* __restrict__ bet,
        float* __restrict__ hout){
    __shared__ float WAt[4096];   // [j][o]
    __shared__ float swT[4096];   // [c][o]
    __shared__ float WAc[64], sbl[64], gl[64], bl[64];
    int tid = threadIdx.x;
    int b = blockIdx.x >> 6;
    int p = ((blockIdx.x & 63) << 8) + tid;
    const float* wab = WAg + b*4160;
    for (int idx = tid; idx < 4096; idx += 256){
        int j = idx >> 6, o = idx & 63;
        WAt[idx] = wab[o*65 + j];
        swT[idx] = sw[o*64 + j];
    }
    if (tid < 64){ WAc[tid] = wab[tid*65+64]; sbl[tid] = sb[tid]; gl[tid] = gam[tid]; bl[tid] = bet[tid]; }
    __syncthreads();
    float acc[64];
    #pragma unroll
    for (int o = 0; o < 64; ++o) acc[o] = 0.f;
    const float* Ab = A + (size_t)b*64*P_ + p;
    #pragma unroll 1
    for (int j = 0; j < 64; ++j){
        float aj = Ab[(size_t)j*P_];
        const float* wrow = WAt + j*64;
        #pragma unroll
        for (int o = 0; o < 64; ++o) acc[o] += aj*wrow[o];
    }
    #pragma unroll 1
    for (int c = 0; c < 64; ++c){
        float hv = hin[((size_t)b*64+c)*P_ + p];
        const float* wrow = swT + c*64;
        #pragma unroll
        for (int o = 0; o < 64; ++o) acc[o] += hv*wrow[o];
    }
    float mu = 0.f;
    #pragma unroll
    for (int o = 0; o < 64; ++o){ acc[o] += WAc[o] + sbl[o]; mu += acc[o]; }
    mu *= (1.0f/64.0f);
    float var = 0.f;
    #pragma unroll
    for (int o = 0; o < 64; ++o){ float d = acc[o]-mu; var += d*d; }
    var *= (1.0f/64.0f);
    float rs = 1.0f/sqrtf(var + 1e-6f);
    float* hb = hout + (size_t)b*64*P_ + p;
    #pragma unroll
    for (int o = 0; o < 64; ++o){
        float zn = (acc[o]-mu)*rs*gl[o] + bl[o];
        hb[(size_t)o*P_] = gelu_f(zn);
    }
}

// ---------------- final projection ----------------
__global__ __launch_bounds__(256) void k_proj(const float* __restrict__ h,
        const float* __restrict__ pw, const float* __restrict__ pb,
        float* __restrict__ out){
    int t = blockIdx.x*256 + threadIdx.x;
    int b = t >> 14, p = t & (P_-1);
    const float* hb = h + (size_t)b*64*P_ + p;
    float s = pb[0];
    for (int c = 0; c < 64; ++c) s += pw[c]*hb[(size_t)c*P_];
    out[t] = s;
}

extern "C" void kernel_launch(void* const* d_in, const int* in_sizes, int n_in,
                              void* d_out, int out_size, void* d_ws, size_t ws_size,
                              hipStream_t stream){
    const float* x      = (const float*)d_in[0];
    const float* lift_w = (const float*)d_in[1];
    const float* lift_b = (const float*)d_in[2];
    const float* w0     = (const float*)d_in[3];
    const float* b0     = (const float*)d_in[4];
    const float* w1     = (const float*)d_in[5];
    const float* b1     = (const float*)d_in[6];
    const float* wf     = (const float*)d_in[7];
    const float* bf     = (const float*)d_in[8];
    const float* wr0 = (const float*)d_in[9];
    const float* wi0 = (const float*)d_in[10];
    const float* sw0 = (const float*)d_in[11];
    const float* sb0 = (const float*)d_in[12];
    const float* g0  = (const float*)d_in[13];
    const float* be0 = (const float*)d_in[14];
    const float* wr1 = (const float*)d_in[15];
    const float* wi1 = (const float*)d_in[16];
    const float* sw1 = (const float*)d_in[17];
    const float* sb1 = (const float*)d_in[18];
    const float* g1  = (const float*)d_in[19];
    const float* be1 = (const float*)d_in[20];
    const float* pw  = (const float*)d_in[21];
    const float* pb  = (const float*)d_in[22];
    float* out = (float*)d_out;
    float* ws = (float*)d_ws;

    float*  h0  = ws;                        // 4,194,304 f
    float*  h1  = ws + 4194304;              // 4,194,304 f
    float*  A   = ws + 8388608;              // 4,194,304 f  (layout [b][j][p])
    float*  R   = ws + 12582912;             // union: Z0 (4,194,304) / Sp (512*4225) / HAp (1024*4160)
    float*  Lfg = ws + 16842752;             // 16,900 f
    float*  HA  = ws + 16859652;             // 16,640 f
    float2* Ug  = (float2*)(ws + 16876292);  // 16,640 float2
    float*  cRe = ws + 16909572;
    float*  cIm = ws + 16975108;
    float*  mRe = ws + 17040644;
    float*  mIm = ws + 17106180;
    float*  WA  = ws + 17171716;
    (void)ws_size; (void)in_sizes; (void)n_in; (void)out_size;

    k_lift<<<256,256,0,stream>>>(x, lift_w, lift_b, h0);
    k_mlp0<<<256,256,0,stream>>>(h0, w0, b0, R);      // Z0 in R
    k_mlp1<<<256,256,0,stream>>>(R, w1, b1, A);
    k_sgram_part<<<512,256,0,stream>>>(A, R);         // Sp overwrites Z0 (done)
    k_chol<<<4,256,0,stream>>>(R, Lfg);
    k_mgs<<<4,1024,0,stream>>>(Lfg, wf, bf, Ug);

    // block 0
    k_ha_part<<<1024,256,0,stream>>>(h0, A, R);
    k_hred<<<65,256,0,stream>>>(R, HA);
    k_coeff<<<256,256,0,stream>>>(HA, Ug, cRe, cIm);
    k_mixed<<<256,256,0,stream>>>(cRe, cIm, wr0, wi0, mRe, mIm);
    k_wa<<<65,256,0,stream>>>(mRe, mIm, Ug, WA);
    k_yfuse<<<256,256,0,stream>>>(A, WA, h0, sw0, sb0, g0, be0, h1);

    // block 1
    k_ha_part<<<1024,256,0,stream>>>(h1, A, R);
    k_hred<<<65,256,0,stream>>>(R, HA);
    k_coeff<<<256,256,0,stream>>>(HA, Ug, cRe, cIm);
    k_mixed<<<256,256,0,stream>>>(cRe, cIm, wr1, wi1, mRe, mIm);
    k_wa<<<65,256,0,stream>>>(mRe, mIm, Ug, WA);
    k_yfuse<<<256,256,0,stream>>>(A, WA, h1, sw1, sb1, g1, be1, h0);

    k_proj<<<256,256,0,stream>>>(h0, pw, pb, out);
}